// Round 3
// baseline (163.198 us; speedup 1.0000x reference)
//
#include <hip/hip_runtime.h>

#define B_DIM 4096
#define L_DIM 2048
#define TPB   256
#define NW    4
#define NBLK  B_DIM              // one block per ROW (R9)
#define LOG_TAU_INV 0.05129329438755058f   // ln(1/0.95)
#define K2EXP 3.0372527176609756f          // 2*log2(e)/0.95 : exp arg in base-2
#define LN2F  0.6931471805599453f

typedef float v4f __attribute__((ext_vector_type(4)));

// Nontemporal float4 load ('nt'): bypasses cache allocation — avoids the L3
// dirty-line service path left by the harness's input restore (R6: −13.5us).
__device__ __forceinline__ v4f ntload(const float* p) {
    return __builtin_nontemporal_load((const v4f*)p);
}

__device__ __forceinline__ unsigned nib(v4f y) {
    return (y.x > 0.5f ? 1u : 0u) | (y.y > 0.5f ? 2u : 0u)
         | (y.z > 0.5f ? 4u : 0u) | (y.w > 0.5f ? 8u : 0u);
}

// R10 = R9 structure (one block/row, one wave/quarter-row, single up-front
// load burst, one packed scan, one barrier) + two refinements:
//  - __launch_bounds__(TPB,6): cap VGPR at 85 -> 6 waves/SIMD (was 5 at 92).
//  - log2-domain transcendentals: v_exp_f32/v_log_f32 are natively base-2;
//    premultiply the exp arg by 2*log2e/tau and accumulate log2 sums, folding
//    ln2 ONCE per thread (saves ~20 v_mul/lane vs __expf/__logf).
// Keeps R7's BCE diet: one log of the 6-factor product per element-pair
// (clamp at -100 provably inactive: p in (1e-4,1-1e-4) => per-factor log2 >=
// -13.3, product >= 2^-80, well inside f32 range).
__global__ __launch_bounds__(TPB, 6) void milecut_row_kernel(
    const float* __restrict__ trunc,
    const float* __restrict__ view1,
    const float* __restrict__ view2,
    const float* __restrict__ view3,
    const float* __restrict__ labels,
    float* __restrict__ partials)
{
    const int t    = threadIdx.x;
    const int lane = t & 63;
    const int wv   = t >> 6;
    const int row  = blockIdx.x;

    __shared__ unsigned swtot[NW];     // packed per-wave label totals
    __shared__ float    sred[NW][3];   // esum, wtr, bce per wave

    const size_t base = (size_t)row * L_DIM + (size_t)(wv << 9) + 4 * lane;
    const float* Lp = labels + base;
    const float* Tp = trunc  + base;
    const float* P1 = view1  + base;
    const float* P2 = view2  + base;
    const float* P3 = view3  + base;

    // ---- issue ALL 10 loads up-front (single wait point) ----
    v4f y0  = ntload(Lp);        v4f y1  = ntload(Lp + 256);
    v4f t0  = ntload(Tp);        v4f t1  = ntload(Tp + 256);
    v4f w10 = ntload(P1);        v4f w11 = ntload(P1 + 256);
    v4f w20 = ntload(P2);        v4f w21 = ntload(P2 + 256);
    v4f w30 = ntload(P3);        v4f w31 = ntload(P3 + 256);

    // ---- masks + single packed wave scan (waits only on the label loads) ----
    unsigned m0 = nib(y0), m1 = nib(y1);
    unsigned pv = (unsigned)__popc(m0) | ((unsigned)__popc(m1) << 16);
    unsigned incl = pv;
    #pragma unroll
    for (int o = 1; o < 64; o <<= 1) {
        unsigned n = (unsigned)__shfl_up((int)incl, o, 64);
        if (lane >= o) incl += n;
    }
    if (lane == 63) swtot[wv] = incl;
    __syncthreads();

    // prefix over the 8 groups of the row (group order: wv*2, wv*2+1)
    unsigned prefix = 0, total = 0, ownA = swtot[wv] & 0xffffu;
    #pragma unroll
    for (int w = 0; w < NW; ++w) {
        unsigned x = swtot[w];
        unsigned s = (x & 0xffffu) + (x >> 16);
        if (w < wv) prefix += s;
        total += s;
    }
    unsigned eo  = incl - pv;                      // exclusive, packed
    unsigned cb0 = prefix + (eo & 0xffffu);        // cumulative base, group 0
    unsigned cb1 = prefix + ownA + (eo >> 16);     // cumulative base, group 1
    float ftotal = (float)total;

    // ---- fused elementwise over the 4 element-pairs (base-2 domain) ----
    float esum = 0.f, wtr2 = 0.f, bce2 = 0.f;
    float tva[4] = {t0.x,  t0.y,  t0.z,  t0.w};
    float tvb[4] = {t1.x,  t1.y,  t1.z,  t1.w};
    float q1a[4] = {w10.x, w10.y, w10.z, w10.w};
    float q1b[4] = {w11.x, w11.y, w11.z, w11.w};
    float q2a[4] = {w20.x, w20.y, w20.z, w20.w};
    float q2b[4] = {w21.x, w21.y, w21.z, w21.w};
    float q3a[4] = {w30.x, w30.y, w30.z, w30.w};
    float q3b[4] = {w31.x, w31.y, w31.z, w31.w};
    const float dbase = (float)((wv << 9) + 4 * lane + 1) + ftotal;
    #pragma unroll
    for (int j = 0; j < 4; ++j) {
        unsigned c1 = cb0 + (unsigned)__popc(m0 & ((2u << j) - 1u));
        unsigned c2 = cb1 + (unsigned)__popc(m1 & ((2u << j) - 1u));
        float d1 = dbase + (float)j;
        float d2 = d1 + 256.0f;
        // e = 2^(K2*c/d)  (== exp(2c/(tau*d)))
        float e1 = __builtin_amdgcn_exp2f(K2EXP * (float)c1 * __builtin_amdgcn_rcpf(d1));
        float e2 = __builtin_amdgcn_exp2f(K2EXP * (float)c2 * __builtin_amdgcn_rcpf(d2));
        esum += e1 + e2;
        wtr2 += __builtin_amdgcn_logf(tva[j]) * e1
              + __builtin_amdgcn_logf(tvb[j]) * e2;        // log2-domain
        bool p1 = (m0 >> j) & 1u;
        bool p2 = (m1 >> j) & 1u;
        float f1 = p1 ? q1a[j] : 1.f - q1a[j];
        float f2 = p1 ? q2a[j] : 1.f - q2a[j];
        float f3 = p1 ? q3a[j] : 1.f - q3a[j];
        float f4 = p2 ? q1b[j] : 1.f - q1b[j];
        float f5 = p2 ? q2b[j] : 1.f - q2b[j];
        float f6 = p2 ? q3b[j] : 1.f - q3b[j];
        bce2 += __builtin_amdgcn_logf(((f1 * f2) * (f3 * f4)) * (f5 * f6));
    }
    // fold base-2 -> natural log ONCE per thread
    float wtr = LN2F * wtr2 + LOG_TAU_INV * esum;
    float bce = LN2F * bce2;

    // ---- wave-local reduce, then one cross-wave combine ----
    #pragma unroll
    for (int o = 32; o > 0; o >>= 1) {
        esum += __shfl_down(esum, o, 64);
        wtr  += __shfl_down(wtr,  o, 64);
        bce  += __shfl_down(bce,  o, 64);
    }
    if (lane == 0) { sred[wv][0] = esum; sred[wv][1] = wtr; sred[wv][2] = bce; }
    __syncthreads();
    if (t == 0) {
        float es = sred[0][0] + sred[1][0] + sred[2][0] + sred[3][0];
        float wt = sred[0][1] + sred[1][1] + sred[2][1] + sred[3][1];
        float bc = sred[0][2] + sred[1][2] + sred[2][2] + sred[3][2];
        partials[row]        = wt / es;     // this row's sum_j log(t/tau)*q_j
        partials[NBLK + row] = bc;          // raw combined bce sum
    }
}

__global__ __launch_bounds__(TPB) void milecut_final_kernel(
    const float* __restrict__ partials, float* __restrict__ out)
{
    const int t = threadIdx.x;
    const float4* p4 = (const float4*)partials;   // 2048 f4: 0..1023 trunc, 1024..2047 bce
    float st = 0.f, sb = 0.f;
    #pragma unroll
    for (int i = 0; i < 4; ++i) {
        float4 a = p4[t + 256 * i];
        float4 b = p4[1024 + t + 256 * i];
        st += (a.x + a.y) + (a.z + a.w);
        sb += (b.x + b.y) + (b.z + b.w);
    }
    #pragma unroll
    for (int o = 32; o > 0; o >>= 1) {
        st += __shfl_down(st, o, 64);
        sb += __shfl_down(sb, o, 64);
    }
    __shared__ float s1[NW], s2[NW];
    const int lane = t & 63, wv = t >> 6;
    if (lane == 0) { s1[wv] = st; s2[wv] = sb; }
    __syncthreads();
    if (t == 0) {
        double St = 0.0, Sb = 0.0;
        #pragma unroll
        for (int w = 0; w < NW; ++w) { St += (double)s1[w]; Sb += (double)s2[w]; }
        double trunc_loss = -St / (double)B_DIM;                         // -sum(log*q)/B
        double vsum = -Sb / ((double)B_DIM * (double)L_DIM * (double)B_DIM);
        out[0] = (float)(0.5 * trunc_loss + 0.5 * vsum);
    }
}

extern "C" void kernel_launch(void* const* d_in, const int* in_sizes, int n_in,
                              void* d_out, int out_size, void* d_ws, size_t ws_size,
                              hipStream_t stream) {
    const float* trunc  = (const float*)d_in[0];
    const float* v1     = (const float*)d_in[1];
    const float* v2     = (const float*)d_in[2];
    const float* v3     = (const float*)d_in[3];
    const float* labels = (const float*)d_in[4];

    float* partials = (float*)d_ws;  // 2*NBLK*4 = 32 KB used

    milecut_row_kernel<<<NBLK, TPB, 0, stream>>>(trunc, v1, v2, v3, labels, partials);
    milecut_final_kernel<<<1, TPB, 0, stream>>>(partials, (float*)d_out);
}